// Round 5
// baseline (1229.764 us; speedup 1.0000x reference)
//
#include <hip/hip_runtime.h>

typedef __attribute__((ext_vector_type(8))) short  short8;   // 8 x bf16 bits (4 VGPRs) — MFMA A/B frag
typedef __attribute__((ext_vector_type(4))) float  float4v;  // MFMA C/D frag
typedef __attribute__((ext_vector_type(4))) float  float4a;  // 16B global load

#define SEQ   2048
#define DHEAD 128
#define NH    32
#define NB    2
#define BM    64      // q rows per block (16 per wave x 4 waves)
#define BN    64      // k cols per tile
#define KSTR  136     // LDS row stride for Q/K tiles (128 + 8 pad)
#define VSTR  72      // LDS row stride for V^T tile  (64 + 8 pad)
#define PSTR  72      // LDS row stride for per-wave P tile (64 + 8 pad)

#define NEG_BIG (-1e30f)

__device__ __forceinline__ unsigned short f2bf(float x) {
    union { float f; unsigned int u; } un; un.f = x;
    unsigned int r = un.u + 0x7fffu + ((un.u >> 16) & 1u);   // round-to-nearest-even
    return (unsigned short)(r >> 16);
}

// Flash attention, causal. fp32 inputs (converted to bf16 at staging),
// fp32 output, fp32 softmax state. MFMA 16x16x32 bf16, layouts per guide §3:
//   A-frag: A[m = lane&15][k = (lane>>4)*8 + j]
//   B-frag: B[k = (lane>>4)*8 + j][n = lane&15]
//   C/D   : D[row = (lane>>4)*4 + reg][col = lane&15]
__global__ __launch_bounds__(256, 2)
void attn_fwd(const float* __restrict__ Qg,
              const float* __restrict__ Kg,
              const float* __restrict__ Vg,
              float* __restrict__ Og)
{
    __shared__ __align__(16) unsigned short sQ[BM * KSTR];
    __shared__ __align__(16) unsigned short sK[BN * KSTR];
    __shared__ __align__(16) unsigned short sV[DHEAD * VSTR];   // V transposed: [d][key]
    __shared__ __align__(16) unsigned short sP[4 * 16 * PSTR];  // per-wave P tiles

    const int tid  = threadIdx.x;
    const int wave = tid >> 6;
    const int lane = tid & 63;
    const int quad = lane >> 4;
    const int m16  = lane & 15;

    const int qt = blockIdx.x;          // q tile index
    const int bh = blockIdx.y;          // b*NH + h
    const int q0 = qt * BM;

    const float* Qp = Qg + (size_t)bh * SEQ * DHEAD;
    const float* Kp = Kg + (size_t)bh * SEQ * DHEAD;
    const float* Vp = Vg + (size_t)bh * SEQ * DHEAD;

    // ---- stage Q tile once (fp32 -> bf16, row-major) ----
    for (int i = tid; i < BM * 32; i += 256) {
        int r  = i >> 5;            // 32 chunks of 4 floats per row
        int c4 = (i & 31) << 2;
        float4a v = *(const float4a*)(Qp + (size_t)(q0 + r) * DHEAD + c4);
        unsigned short* dst = &sQ[r * KSTR + c4];
        dst[0] = f2bf(v[0]); dst[1] = f2bf(v[1]);
        dst[2] = f2bf(v[2]); dst[3] = f2bf(v[3]);
    }
    __syncthreads();

    // Q A-frags live in registers for the whole kernel (16 rows x 128 k per wave)
    short8 qf[4];
#pragma unroll
    for (int kc = 0; kc < 4; ++kc)
        qf[kc] = *(const short8*)&sQ[(wave * 16 + m16) * KSTR + kc * 32 + quad * 8];

    float4v accO[8];
#pragma unroll
    for (int i = 0; i < 8; ++i) accO[i] = (float4v){0.f, 0.f, 0.f, 0.f};
    float mst[4] = {NEG_BIG, NEG_BIG, NEG_BIG, NEG_BIG};
    float lst[4] = {0.f, 0.f, 0.f, 0.f};

    const float scale = 0.08838834764831845f;   // 1/sqrt(128)

    for (int kt = 0; kt <= qt; ++kt) {
        const int k0 = kt * BN;
        __syncthreads();   // previous iteration's LDS reads done before restaging

        // ---- stage K tile (fp32 -> bf16, row-major) ----
        for (int i = tid; i < BN * 32; i += 256) {
            int r  = i >> 5;
            int c4 = (i & 31) << 2;
            float4a v = *(const float4a*)(Kp + (size_t)(k0 + r) * DHEAD + c4);
            unsigned short* dst = &sK[r * KSTR + c4];
            dst[0] = f2bf(v[0]); dst[1] = f2bf(v[1]);
            dst[2] = f2bf(v[2]); dst[3] = f2bf(v[3]);
        }
        // ---- stage V tile transposed: sV[d][key] (fp32 -> bf16) ----
        for (int i = tid; i < BN * 32; i += 256) {
            int r  = i >> 5;
            int c4 = (i & 31) << 2;
            float4a v = *(const float4a*)(Vp + (size_t)(k0 + r) * DHEAD + c4);
#pragma unroll
            for (int j = 0; j < 4; ++j)
                sV[(c4 + j) * VSTR + r] = f2bf(v[j]);
        }
        __syncthreads();

        // ---- S = Q K^T (16 rows x 64 cols per wave) ----
        float4v accS[4];
#pragma unroll
        for (int nt = 0; nt < 4; ++nt) accS[nt] = (float4v){0.f, 0.f, 0.f, 0.f};
#pragma unroll
        for (int kc = 0; kc < 4; ++kc) {
#pragma unroll
            for (int nt = 0; nt < 4; ++nt) {
                short8 bfr = *(const short8*)&sK[(nt * 16 + m16) * KSTR + kc * 32 + quad * 8];
                accS[nt] = __builtin_amdgcn_mfma_f32_16x16x32_bf16(qf[kc], bfr, accS[nt], 0, 0, 0);
            }
        }

        // ---- scale + causal mask (diagonal tile only, since BM==BN) ----
        if (kt == qt) {
#pragma unroll
            for (int nt = 0; nt < 4; ++nt)
#pragma unroll
                for (int r = 0; r < 4; ++r) {
                    int kcol = k0 + nt * 16 + m16;
                    int qrow = q0 + wave * 16 + quad * 4 + r;
                    float s  = accS[nt][r] * scale;
                    accS[nt][r] = (kcol > qrow) ? NEG_BIG : s;
                }
        } else {
#pragma unroll
            for (int nt = 0; nt < 4; ++nt)
#pragma unroll
                for (int r = 0; r < 4; ++r)
                    accS[nt][r] *= scale;
        }

        // ---- online softmax (row = quad*4 + r; 16 lanes per row, shfl_xor 1..8) ----
        float alpha[4];
#pragma unroll
        for (int r = 0; r < 4; ++r) {
            float mx = fmaxf(fmaxf(accS[0][r], accS[1][r]), fmaxf(accS[2][r], accS[3][r]));
            mx = fmaxf(mx, __shfl_xor(mx, 1));
            mx = fmaxf(mx, __shfl_xor(mx, 2));
            mx = fmaxf(mx, __shfl_xor(mx, 4));
            mx = fmaxf(mx, __shfl_xor(mx, 8));
            float mnew = fmaxf(mst[r], mx);
            alpha[r] = __expf(mst[r] - mnew);
            mst[r] = mnew;
        }
#pragma unroll
        for (int r = 0; r < 4; ++r) {
            float rs = 0.f;
#pragma unroll
            for (int nt = 0; nt < 4; ++nt) {
                float p = __expf(accS[nt][r] - mst[r]);
                accS[nt][r] = p;
                rs += p;
            }
            rs += __shfl_xor(rs, 1);
            rs += __shfl_xor(rs, 2);
            rs += __shfl_xor(rs, 4);
            rs += __shfl_xor(rs, 8);
            lst[r] = lst[r] * alpha[r] + rs;
        }

        // ---- rescale O by alpha ----
#pragma unroll
        for (int dt = 0; dt < 8; ++dt)
#pragma unroll
            for (int r = 0; r < 4; ++r)
                accO[dt][r] *= alpha[r];

        // ---- P: C-layout regs -> per-wave LDS -> A-layout frags ----
        unsigned short* pw = &sP[wave * 16 * PSTR];
#pragma unroll
        for (int nt = 0; nt < 4; ++nt)
#pragma unroll
            for (int r = 0; r < 4; ++r)
                pw[(quad * 4 + r) * PSTR + nt * 16 + m16] = f2bf(accS[nt][r]);

        short8 pf[2];
#pragma unroll
        for (int kc2 = 0; kc2 < 2; ++kc2)
            pf[kc2] = *(const short8*)&pw[m16 * PSTR + kc2 * 32 + quad * 8];

        // ---- O += P V ----
#pragma unroll
        for (int kc2 = 0; kc2 < 2; ++kc2)
#pragma unroll
            for (int dt = 0; dt < 8; ++dt) {
                short8 vf = *(const short8*)&sV[(dt * 16 + m16) * VSTR + kc2 * 32 + quad * 8];
                accO[dt] = __builtin_amdgcn_mfma_f32_16x16x32_bf16(pf[kc2], vf, accO[dt], 0, 0, 0);
            }
    }

    // ---- epilogue: out[b][q][h*128 + d], fp32 ----
    const int b = bh >> 5;
    const int h = bh & 31;
    float invl[4];
#pragma unroll
    for (int r = 0; r < 4; ++r) invl[r] = 1.0f / lst[r];
#pragma unroll
    for (int dt = 0; dt < 8; ++dt)
#pragma unroll
        for (int r = 0; r < 4; ++r) {
            int q = q0 + wave * 16 + quad * 4 + r;
            int d = dt * 16 + m16;
            Og[(size_t)(b * SEQ + q) * (NH * DHEAD) + h * DHEAD + d] = accO[dt][r] * invl[r];
        }
}

extern "C" void kernel_launch(void* const* d_in, const int* in_sizes, int n_in,
                              void* d_out, int out_size, void* d_ws, size_t ws_size,
                              hipStream_t stream) {
    const float* Q = (const float*)d_in[0];
    const float* K = (const float*)d_in[1];
    const float* V = (const float*)d_in[2];
    float* O = (float*)d_out;
    dim3 grid(SEQ / BM, NB * NH);
    attn_fwd<<<grid, 256, 0, stream>>>(Q, K, V, O);
}